// Round 4
// baseline (10007.720 us; speedup 1.0000x reference)
//
#include <hip/hip_runtime.h>
#include <hip/hip_cooperative_groups.h>
#include <cstdint>

// ============================================================================
// EncoderLSTMReal: reverse LSTM (T=200,B=1024,H=512,IN=64) + 2 tanh-MLP heads.
// CONTRACT (established R0-R8):
//   - inputs fp32, dict order; OUTPUT FLOAT32; mu = out[0..32768), logvar next
//   - heads read fp32 h (h_final)
// Round-13 (R4): persistent cooperative LSTM, register-resident weights.
//   R3 post-mortem: 26 us/step vs 2.9 us MFMA floor — 1 wave/SIMD (130 KB
//   LDS) exposed every latency; B re-staged from L2 every chunk; 200
//   launches. New: ONE cooperative kernel, 200 steps inside, grid.sync()
//   between steps. Each wave owns 16 cols: Bh[18]+Bl[18] f16x8 = 144 VGPR
//   loaded ONCE. h carried as hi/lo f16 planes (split at cell time, same
//   quantization as R3's stage-time split => same numerics); fp32 h_final
//   written at s==199 for heads. c resident in LDS; biases pre-summed.
//   Per chunk/wave: 16 ds_read_b128 + 36 MFMA (3-matmul split hi/lo).
// ws: [0,256) maxm; [256,+4.26MB) z; h_final f32 @4260096; whi @6357248;
//     wlo @8716544; hhi[2] @11075840; hlo[2] @13172992; end 15270144.
// ============================================================================

namespace cg = cooperative_groups;

typedef _Float16 f16;
typedef __attribute__((ext_vector_type(4))) _Float16 f16x4;
typedef __attribute__((ext_vector_type(8))) _Float16 f16x8;
typedef __attribute__((ext_vector_type(4))) float f32x4;

#define DEV __device__ __forceinline__

DEV float sigf(float x) { return 1.0f / (1.0f + expf(-x)); }

// =================== weight split prep: [2048][576] hi/lo ===================
__global__ void __launch_bounds__(256)
wprep_kernel(const float* __restrict__ w_ih, const float* __restrict__ w_hh,
             f16* __restrict__ whi, f16* __restrict__ wlo) {
  int idx = blockIdx.x * 256 + threadIdx.x;   // over 2048*576
  if (idx >= 2048 * 576) return;
  int n = idx / 576, k = idx - n * 576;
  float v = (k < 64) ? w_ih[n * 64 + k] : w_hh[(size_t)n * 512 + (k - 64)];
  f16 h = (f16)v;
  whi[idx] = h;
  wlo[idx] = (f16)(v - (float)h);
}

// ======================= persistent LSTM (cooperative) ======================
// grid 256 = 16 mt x 16 nt; block 512 = 8 waves.
// wave w: gate = w>>1, jj-half = w&1 -> cols gate*512 + nt*32 + (w&1)*16 + 16.
// rows: all 64 (4 tiles of 16). K = 576 = 9 chunks x 64 (2 ks of 32).
// LDS A frag-order: line L = ((rt*2+ks)*2+p), 64 lanes x 16B each.
__global__ void __launch_bounds__(512, 2)
lstm_persist(const float* __restrict__ x, const float* __restrict__ a,
             const f16* __restrict__ whi, const f16* __restrict__ wlo,
             const float* __restrict__ b_ih, const float* __restrict__ b_hh,
             f16* __restrict__ hhi, f16* __restrict__ hlo,
             float* __restrict__ h_final, const float* __restrict__ maxm_p) {
  __shared__ f16 sA[2][8192];       // [buf][(line*64+lane)*8]
  __shared__ float sG[64 * 132];    // gates fp32, col = gate*32 + jj
  __shared__ float cL[64 * 33];     // cell state, resident 200 steps
  __shared__ float bsum[128];       // b_ih + b_hh per block col

  const int tid = threadIdx.x;
  const int lane = tid & 63;
  const int w = tid >> 6;           // wave 0..7
  const int bid = blockIdx.x;
  const int mt = bid >> 4, nt = bid & 15;
  const int m0 = mt * 64;

  // ---- one-time init ----
  if (tid < 128) {
    int g = tid >> 5, jj = tid & 31;
    int n = g * 512 + nt * 32 + jj;
    bsum[tid] = b_ih[n] + b_hh[n];
  }
  for (int i = tid; i < 64 * 33; i += 512) cL[i] = 0.f;

  // ---- one-time: B fragments -> registers (144 VGPR) ----
  const int cb = (w >> 1) * 512 + nt * 32 + (w & 1) * 16;
  const int bcol = cb + (lane & 15);
  const int bk8 = (lane >> 4) * 8;
  f16x8 Bh[18], Bl[18];
#pragma unroll
  for (int t = 0; t < 18; t++) {
    Bh[t] = *(const f16x8*)&whi[(size_t)bcol * 576 + t * 32 + bk8];
    Bl[t] = *(const f16x8*)&wlo[(size_t)bcol * 576 + t * 32 + bk8];
  }
  const float mxm = *maxm_p;
  cg::grid_group grid = cg::this_grid();
  __syncthreads();

  for (int s = 0; s < 200; s++) {
    const int nch = (s == 0) ? 1 : 9;          // h == 0 at s == 0
    const int bin = s & 1, bout = bin ^ 1;
    const f16* hhi_in = hhi + (size_t)bin * 1024 * 512;
    const f16* hlo_in = hlo + (size_t)bin * 1024 * 512;

    // ---- stage chunk 0 (x_in: 0..47 x, 48..62 a, 63 t) into sA[0] ----
    {
      const float ts = (float)s / mxm;         // exact R3 formula
      size_t srow = (size_t)(199 - s) * 1024 + m0;
      int row = tid >> 3, k8 = (tid & 7) * 8;
      float v[8];
#pragma unroll
      for (int e = 0; e < 8; e++) {
        int k = k8 + e;
        if (k < 48)      v[e] = x[(srow + row) * 48 + k];
        else if (k < 63) v[e] = a[(srow + row) * 15 + (k - 48)];
        else             v[e] = ts;
      }
      f16x8 hi, lo;
#pragma unroll
      for (int e = 0; e < 8; e++) {
        f16 h8 = (f16)v[e];
        hi[e] = h8; lo[e] = (f16)(v[e] - (float)h8);
      }
      int rt = row >> 4, ks = k8 >> 5;
      int ln = (((k8 & 31) >> 3) << 4) | (row & 15);
      int lhi = ((rt * 2 + ks) * 2 + 0) * 64 + ln;
      *(f16x8*)&sA[0][lhi * 8] = hi;
      *(f16x8*)&sA[0][(lhi + 64) * 8] = lo;    // p=1 line = +64 slots
    }
    __syncthreads();

    f32x4 acc[4];
#pragma unroll
    for (int r = 0; r < 4; r++) acc[r] = (f32x4){0.f, 0.f, 0.f, 0.f};

    int cur = 0;
#pragma unroll
    for (int ch = 0; ch < 9; ch++) {
      if (ch < nch) {
        const bool pref = (ch + 1 < nch);
        uint4 pa[2];
        if (pref) {                            // prefetch h chunk ch (for ch+1)
#pragma unroll
          for (int i2 = 0; i2 < 2; i2++) {
            int L = i2 * 8 + w;
            int rt = L >> 2, ks = (L >> 1) & 1, p = L & 1;
            const f16* pl = p ? hlo_in : hhi_in;
            size_t ad = (size_t)(m0 + rt * 16 + (lane & 15)) * 512 +
                        ch * 64 + ks * 32 + (lane >> 4) * 8;
            pa[i2] = *(const uint4*)&pl[ad];
          }
        }
        const f16* buf = sA[cur];
#pragma unroll
        for (int ks = 0; ks < 2; ks++) {
          const int t = ch * 2 + ks;           // static (unrolled)
          f16x8 Ah[4], Al[4];
#pragma unroll
          for (int rt = 0; rt < 4; rt++) {
            Ah[rt] = *(const f16x8*)&buf[(((rt * 2 + ks) * 2 + 0) * 64 + lane) * 8];
            Al[rt] = *(const f16x8*)&buf[(((rt * 2 + ks) * 2 + 1) * 64 + lane) * 8];
          }
#pragma unroll
          for (int rt = 0; rt < 4; rt++)
            acc[rt] = __builtin_amdgcn_mfma_f32_16x16x32_f16(Ah[rt], Bh[t], acc[rt], 0, 0, 0);
#pragma unroll
          for (int rt = 0; rt < 4; rt++)
            acc[rt] = __builtin_amdgcn_mfma_f32_16x16x32_f16(Al[rt], Bh[t], acc[rt], 0, 0, 0);
#pragma unroll
          for (int rt = 0; rt < 4; rt++)
            acc[rt] = __builtin_amdgcn_mfma_f32_16x16x32_f16(Ah[rt], Bl[t], acc[rt], 0, 0, 0);
        }
        if (pref) {
#pragma unroll
          for (int i2 = 0; i2 < 2; i2++) {
            int L = i2 * 8 + w;
            *(uint4*)&sA[cur ^ 1][(L * 64 + lane) * 8] = pa[i2];
          }
        }
        __syncthreads();
        cur ^= 1;
      }
    }

    // ---- acc -> sG (C/D: col=lane&15, row=(lane>>4)*4+i; R3-verified) ----
    {
      const int colb = (w >> 1) * 32 + (w & 1) * 16 + (lane & 15);
#pragma unroll
      for (int rt = 0; rt < 4; rt++) {
        int rowb = rt * 16 + (lane >> 4) * 4;
#pragma unroll
        for (int i = 0; i < 4; i++)
          sG[(rowb + i) * 132 + colb] = acc[rt][i];
      }
    }
    __syncthreads();

    // ---- cell: 4 elems/thread; c in LDS; h -> hi/lo f16 planes ----
    {
      f16* hhi_out = hhi + (size_t)bout * 1024 * 512;
      f16* hlo_out = hlo + (size_t)bout * 1024 * 512;
      int m = tid >> 3, jq = (tid & 7) * 4;
      f16x4 hh, hl;
      f32x4 hf;
#pragma unroll
      for (int u = 0; u < 4; u++) {
        int j = jq + u;
        float gi = sG[m * 132 +       j] + bsum[      j];
        float gf = sG[m * 132 +  32 + j] + bsum[ 32 + j];
        float gg = sG[m * 132 +  64 + j] + bsum[ 64 + j];
        float go = sG[m * 132 +  96 + j] + bsum[ 96 + j];
        float c = sigf(gf) * cL[m * 33 + j] + sigf(gi) * tanhf(gg);
        cL[m * 33 + j] = c;
        float h = sigf(go) * tanhf(c);
        f16 h8 = (f16)h;
        hh[u] = h8; hl[u] = (f16)(h - (float)h8);
        hf[u] = h;
      }
      size_t ob = (size_t)(m0 + m) * 512 + nt * 32 + jq;
      *(f16x4*)&hhi_out[ob] = hh;
      *(f16x4*)&hlo_out[ob] = hl;
      if (s == 199) *(f32x4*)&h_final[ob] = hf;
    }
    grid.sync();
  }
}

// ============================= max(m) =======================================
__global__ void __launch_bounds__(1024)
maxm_kernel(const float* __restrict__ mv, float* __restrict__ out) {
  __shared__ float red[1024];
  int tid = threadIdx.x;
  float mx = -3.0e38f;
  for (int i = tid; i < 200 * 1024; i += 1024) mx = fmaxf(mx, mv[i]);
  red[tid] = mx;
  __syncthreads();
  for (int s = 512; s > 0; s >>= 1) {
    if (tid < s) red[tid] = fmaxf(red[tid], red[tid + s]);
    __syncthreads();
  }
  if (tid == 0) *out = red[0];
}

// ============ head layer 1: z = tanh(h @ {lw1,vw1}^T + b1) ==================
__global__ void __launch_bounds__(256, 2)
head1_valu(const float* __restrict__ h, const float* __restrict__ lw1,
           const float* __restrict__ lb1, const float* __restrict__ vw1,
           const float* __restrict__ vb1, float* __restrict__ z) {
  __shared__ float sAT[64 * 68];
  const int tid = threadIdx.x;
  const int rg = tid & 15;
  const int cgrp = tid >> 4;
  const int bid = blockIdx.x;
  const int mt = bid & 15, nt = bid >> 4;
  const int m0 = mt * 64;
  const int nb = nt * 64 + cgrp * 4;

  const float* wr[4];
  float bias[4];
  int hdv[4], wnv[4], valid[4];
#pragma unroll
  for (int c = 0; c < 4; c++) {
    int n = nb + c;
    valid[c] = (n < 1026);
    int hd = valid[c] ? (n >= 513) : 0;
    int wn = valid[c] ? (n - hd * 513) : 0;
    hdv[c] = hd; wnv[c] = wn;
    wr[c] = (hd ? vw1 : lw1) + (size_t)wn * 512;
    bias[c] = valid[c] ? (hd ? vb1[wn] : lb1[wn]) : 0.f;
  }

  float acc[4][4];
#pragma unroll
  for (int i = 0; i < 4; i++)
#pragma unroll
    for (int c = 0; c < 4; c++) acc[i][c] = 0.f;

  for (int ch = 0; ch < 8; ch++) {
    int k0 = ch * 64;
    for (int idx = tid; idx < 4096; idx += 256) {
      int row = idx >> 6, k = idx & 63;
      sAT[k * 68 + row] = h[(size_t)(m0 + row) * 512 + k0 + k];
    }
    __syncthreads();
#pragma unroll 4
    for (int k4 = 0; k4 < 16; k4++) {
      f32x4 wv[4];
#pragma unroll
      for (int c = 0; c < 4; c++)
        wv[c] = *(const f32x4*)(wr[c] + k0 + k4 * 4);
      f32x4 rv[4];
#pragma unroll
      for (int kk = 0; kk < 4; kk++)
        rv[kk] = *(const f32x4*)&sAT[(k4 * 4 + kk) * 68 + rg * 4];
#pragma unroll
      for (int kk = 0; kk < 4; kk++)
#pragma unroll
        for (int c = 0; c < 4; c++) {
          acc[0][c] += rv[kk][0] * wv[c][kk];
          acc[1][c] += rv[kk][1] * wv[c][kk];
          acc[2][c] += rv[kk][2] * wv[c][kk];
          acc[3][c] += rv[kk][3] * wv[c][kk];
        }
    }
    __syncthreads();
  }
#pragma unroll
  for (int c = 0; c < 4; c++) {
    if (!valid[c]) continue;
#pragma unroll
    for (int i = 0; i < 4; i++) {
      int m = m0 + rg * 4 + i;
      z[(size_t)hdv[c] * 1024 * 520 + (size_t)m * 520 + wnv[c]] =
          tanhf(acc[i][c] + bias[c]);
    }
  }
}

// ============ head layer 2: out = tanh(z @ {lw2,vw2}^T + b2) ================
__global__ void __launch_bounds__(256)
head2_valu(const float* __restrict__ z, const float* __restrict__ lw2,
           const float* __restrict__ lb2, const float* __restrict__ vw2,
           const float* __restrict__ vb2, float* __restrict__ out) {
  __shared__ float sZ[8 * 133];
  __shared__ float sW[32 * 133];
  const int tid = threadIdx.x;
  const int bid = blockIdx.x;
  const int gr0 = bid * 8;
  const int hd = gr0 >> 10;
  const int b0 = gr0 & 1023;
  const float* w2 = hd ? vw2 : lw2;
  const float* b2 = hd ? vb2 : lb2;
  const float* zh = z + (size_t)hd * 1024 * 520;
  const int rloc = tid >> 5, col = tid & 31;
  float acc = 0.f;

  for (int ch = 0; ch < 5; ch++) {
    int kc = ch * 128;
    for (int idx = tid; idx < 1024; idx += 256) {
      int row = idx >> 7, k = idx & 127;
      int kk = kc + k;
      sZ[row * 133 + k] = (kk < 513) ? zh[(size_t)(b0 + row) * 520 + kk] : 0.f;
    }
    for (int idx = tid; idx < 4096; idx += 256) {
      int row = idx >> 7, k = idx & 127;
      int kk = kc + k;
      sW[row * 133 + k] = (kk < 513) ? w2[(size_t)row * 513 + kk] : 0.f;
    }
    __syncthreads();
#pragma unroll 8
    for (int k = 0; k < 128; k++)
      acc += sZ[rloc * 133 + k] * sW[col * 133 + k];
    __syncthreads();
  }
  out[(size_t)hd * 32768 + (size_t)(b0 + rloc) * 32 + col] = tanhf(acc + b2[col]);
}

// ============================================================================
extern "C" void kernel_launch(void* const* d_in, const int* in_sizes, int n_in,
                              void* d_out, int out_size, void* d_ws, size_t ws_size,
                              hipStream_t stream) {
  (void)in_sizes; (void)n_in; (void)out_size; (void)ws_size;
  const float* x    = (const float*)d_in[0];
  const float* a    = (const float*)d_in[1];
  const float* mm   = (const float*)d_in[2];
  const float* w_ih = (const float*)d_in[3];
  const float* w_hh = (const float*)d_in[4];
  const float* b_ih = (const float*)d_in[5];
  const float* b_hh = (const float*)d_in[6];
  const float* lw1  = (const float*)d_in[7];
  const float* lb1  = (const float*)d_in[8];
  const float* lw2  = (const float*)d_in[9];
  const float* lb2  = (const float*)d_in[10];
  const float* vw1  = (const float*)d_in[11];
  const float* vb1  = (const float*)d_in[12];
  const float* vw2  = (const float*)d_in[13];
  const float* vb2  = (const float*)d_in[14];

  char* wsb = (char*)d_ws;
  float* maxm   = (float*)wsb;                       // 256 B
  float* z      = (float*)(wsb + 256);               // 2x1024x520 f32
  float* h_fin  = (float*)(wsb + 4260096);           // 1024x512 f32
  f16*   whi    = (f16*)(wsb + 6357248);             // 2048x576 f16
  f16*   wlo    = (f16*)(wsb + 8716544);             // 2048x576 f16
  f16*   hhi    = (f16*)(wsb + 11075840);            // [2][1024][512] f16
  f16*   hlo    = (f16*)(wsb + 13172992);            // [2][1024][512] f16

  maxm_kernel<<<1, 1024, 0, stream>>>(mm, maxm);
  wprep_kernel<<<4608, 256, 0, stream>>>(w_ih, w_hh, whi, wlo);

  {
    const float* xa = x; const float* aa = a;
    const f16* whia = whi; const f16* wloa = wlo;
    const float* biha = b_ih; const float* bhha = b_hh;
    f16* hhia = hhi; f16* hloa = hlo;
    float* hfa = h_fin; const float* mxa = maxm;
    void* kargs[] = {&xa, &aa, &whia, &wloa, &biha, &bhha,
                     &hhia, &hloa, &hfa, &mxa};
    hipLaunchCooperativeKernel((void*)lstm_persist, dim3(256), dim3(512),
                               kargs, 0, stream);
  }

  head1_valu<<<272, 256, 0, stream>>>(h_fin, lw1, lb1, vw1, vb1, z);
  head2_valu<<<256, 256, 0, stream>>>(z, lw2, lb2, vw2, vb2, (float*)d_out);
}

// Round 5
// 8548.683 us; speedup vs baseline: 1.1707x; 1.1707x over previous
//
#include <hip/hip_runtime.h>
#include <hip/hip_cooperative_groups.h>
#include <cstdint>

// ============================================================================
// EncoderLSTMReal: reverse LSTM (T=200,B=1024,H=512,IN=64) + 2 tanh-MLP heads.
// CONTRACT (R0-R8): inputs fp32 dict order; OUTPUT FLOAT32 (mu 0..32768, lv
// next); heads read fp32 h_final.
// Round-14 (R5): persistent coop LSTM, gate-grouped waves, streamed B.
//   R4 post-mortem: VGPR=116 proves compiler refuses 144-VGPR resident B
//   (spill/remat -> 9.2 MB/step HBM, 50 us/step). R2 lesson: no s_load
//   scalarization either. So B STREAMS from L2 every chunk (proven R3 path),
//   staged via wprep-preswizzled images (coalesced uint4 -> linear LDS).
//   Wave = 16 rows x 16 jj x ALL 4 GATES -> cell fully in registers
//   (no sG, no redistribution barriers, c in 4 VGPRs). 512-thr blocks,
//   grid 256 = 16 mt x 16 jt, 2 waves/SIMD, LDS 96 KB dbuf.
//   Cross-step sync: per-mt 16-block counter barrier (h rows only cross
//   jt, never mt), monotonic counts zeroed by wprep each invocation.
// ws: maxm@0; bar@256; z@512; h_final@4260352; wsw@6357504 (4.5MB);
//     hhi@11076096; hlo@13173248; end 15270400.
// ============================================================================

namespace cg = cooperative_groups;

typedef _Float16 f16;
typedef __attribute__((ext_vector_type(8))) _Float16 f16x8;
typedef __attribute__((ext_vector_type(4))) float f32x4;

#define DEV __device__ __forceinline__

DEV float sigf(float x) { return 1.0f / (1.0f + expf(-x)); }

// ============ weight pre-swizzle: per-(jt,ch) LDS image, + bar zero =========
// wsw uint4 idx = ((jt*9 + ch)*32 + Lb)*64 + lane, Lb = ((g*2+jg)*2+ks)*2+p.
// value: 8 halves of plane p of w[n][kb..kb+7], n = g*512+jt*32+jg*16+(lane&15),
// kb = ch*64 + ks*32 + (lane>>4)*8.  (k<64 -> w_ih, else w_hh.)
__global__ void __launch_bounds__(256)
wprep_kernel(const float* __restrict__ w_ih, const float* __restrict__ w_hh,
             uint4* __restrict__ wsw, unsigned* __restrict__ bar) {
  int idx = blockIdx.x * 256 + threadIdx.x;       // 1152*256 = 294912 exact
  if (blockIdx.x == 0 && threadIdx.x < 16) bar[threadIdx.x] = 0u;
  if (idx >= 16 * 9 * 32 * 64) return;
  int jt = idx / 18432, rem = idx - jt * 18432;
  int ch = rem >> 11, r2 = rem & 2047;
  int Lb = r2 >> 6, lane = r2 & 63;
  int p = Lb & 1, ks = (Lb >> 1) & 1, jg = (Lb >> 2) & 1, g = Lb >> 3;
  int n = g * 512 + jt * 32 + jg * 16 + (lane & 15);
  int kb = ch * 64 + ks * 32 + (lane >> 4) * 8;
  f16x8 o;
#pragma unroll
  for (int e = 0; e < 8; e++) {
    int k = kb + e;
    float v = (k < 64) ? w_ih[n * 64 + k] : w_hh[(size_t)n * 512 + (k - 64)];
    f16 hi = (f16)v;
    o[e] = p ? (f16)(v - (float)hi) : hi;
  }
  wsw[idx] = *(uint4*)&o;
}

// ======================= persistent LSTM (cooperative) ======================
// grid 256 = 16 mt x 16 jt; block 512 = 8 waves = 4 rg x 2 jg.
// wave (rg,jg): rows m0+rg*16..+15, cols = 4 gates x (jt*32 + jg*16 ..+15).
// LDS buf (48 KB): A lines 0..15 (id=(rg*2+ks)*2+p), B lines 16..47 (16+Lb);
// line = 64 lanes x 8 halves; slot addressing is LINEAR in stage id.
__global__ void __launch_bounds__(512, 2)
lstm_persist(const float* __restrict__ x, const float* __restrict__ a,
             const uint4* __restrict__ wsw,
             const float* __restrict__ b_ih, const float* __restrict__ b_hh,
             f16* __restrict__ hhi, f16* __restrict__ hlo,
             float* __restrict__ h_final, const float* __restrict__ maxm_p,
             unsigned* __restrict__ bar) {
  __shared__ f16 sAB[2][24576];     // [buf][ A: 8192 halves | B: 16384 ]

  const int tid = threadIdx.x;
  const int lane = tid & 63;
  const int w = tid >> 6;
  const int rg = w >> 1, jg = w & 1;
  const int bid = blockIdx.x;
  const int mt = bid >> 4, jt = bid & 15;
  const int m0 = mt * 64;
  const int jjcol = jt * 32 + jg * 16 + (lane & 15);

  float bias[4];
#pragma unroll
  for (int g = 0; g < 4; g++)
    bias[g] = b_ih[g * 512 + jjcol] + b_hh[g * 512 + jjcol];
  float cc[4] = {0.f, 0.f, 0.f, 0.f};
  const float mxm = *maxm_p;

  for (int s = 0; s < 200; s++) {
    const int nch = (s == 0) ? 1 : 9;
    const int bin = s & 1, bout = bin ^ 1;
    const f16* hhi_in = hhi + (size_t)bin * 1024 * 512;
    const f16* hlo_in = hlo + (size_t)bin * 1024 * 512;

    // ---- prologue: stage chunk 0 (x|a|t split hi/lo) + B chunk 0 ----
    {
#pragma unroll
      for (int i = 0; i < 4; i++) {
        int id = tid + i * 512;
        uint4 v = wsw[(size_t)(jt * 9 + 0) * 2048 + id];
        *(uint4*)&sAB[0][8192 + id * 8] = v;
      }
      const float ts = (float)s / mxm;
      size_t srow = (size_t)(199 - s) * 1024 + m0;
      int row = tid >> 3, k8 = (tid & 7) * 8;
      float v[8];
#pragma unroll
      for (int e = 0; e < 8; e++) {
        int k = k8 + e;
        if (k < 48)      v[e] = x[(srow + row) * 48 + k];
        else if (k < 63) v[e] = a[(srow + row) * 15 + (k - 48)];
        else             v[e] = ts;
      }
      f16x8 hi, lo;
#pragma unroll
      for (int e = 0; e < 8; e++) {
        f16 h8 = (f16)v[e];
        hi[e] = h8; lo[e] = (f16)(v[e] - (float)h8);
      }
      int rg2 = row >> 4, ks2 = k8 >> 5;
      int ln = (((k8 & 31) >> 3) << 4) | (row & 15);
      int Lhi = (rg2 * 2 + ks2) * 2;
      *(f16x8*)&sAB[0][(Lhi * 64 + ln) * 8] = hi;
      *(f16x8*)&sAB[0][((Lhi + 1) * 64 + ln) * 8] = lo;
    }
    __syncthreads();

    f32x4 acc[4];
#pragma unroll
    for (int g = 0; g < 4; g++) acc[g] = (f32x4){0.f, 0.f, 0.f, 0.f};

    int cur = 0;
    for (int ch = 0; ch < nch; ch++) {
      const bool pref = (ch + 1 < nch);
      uint4 pa[2], pb[4];
      if (pref) {
#pragma unroll
        for (int i = 0; i < 2; i++) {          // A: h chunk ch (k = ch*64+..)
          int id = tid + i * 512;
          int La = id >> 6, ln = id & 63;
          int rg2 = La >> 2, ks2 = (La >> 1) & 1, p2 = La & 1;
          const f16* pl = p2 ? hlo_in : hhi_in;
          size_t ad = (size_t)(m0 + rg2 * 16 + (ln & 15)) * 512 +
                      ch * 64 + ks2 * 32 + (ln >> 4) * 8;
          pa[i] = *(const uint4*)&pl[ad];
        }
#pragma unroll
        for (int i = 0; i < 4; i++) {          // B: chunk ch+1 image
          int id = tid + i * 512;
          pb[i] = wsw[(size_t)(jt * 9 + ch + 1) * 2048 + id];
        }
      }

      const f16* buf = sAB[cur];
#pragma unroll
      for (int ks = 0; ks < 2; ks++) {
        f16x8 Ah = *(const f16x8*)&buf[(((rg * 2 + ks) * 2 + 0) * 64 + lane) * 8];
        f16x8 Al = *(const f16x8*)&buf[(((rg * 2 + ks) * 2 + 1) * 64 + lane) * 8];
        f16x8 Bh[4], Bl[4];
#pragma unroll
        for (int g = 0; g < 4; g++) {
          int base = 8192 + ((((g * 2 + jg) * 2 + ks) * 2) * 64 + lane) * 8;
          Bh[g] = *(const f16x8*)&buf[base];
          Bl[g] = *(const f16x8*)&buf[base + 512];   // +1 line = 64*8 halves
        }
        __builtin_amdgcn_s_setprio(1);
#pragma unroll
        for (int g = 0; g < 4; g++)
          acc[g] = __builtin_amdgcn_mfma_f32_16x16x32_f16(Ah, Bh[g], acc[g], 0, 0, 0);
#pragma unroll
        for (int g = 0; g < 4; g++)
          acc[g] = __builtin_amdgcn_mfma_f32_16x16x32_f16(Al, Bh[g], acc[g], 0, 0, 0);
#pragma unroll
        for (int g = 0; g < 4; g++)
          acc[g] = __builtin_amdgcn_mfma_f32_16x16x32_f16(Ah, Bl[g], acc[g], 0, 0, 0);
        __builtin_amdgcn_s_setprio(0);
      }

      if (pref) {
        f16* nb = sAB[cur ^ 1];
#pragma unroll
        for (int i = 0; i < 2; i++) {
          int id = tid + i * 512;
          *(uint4*)&nb[id * 8] = pa[i];              // A region linear
        }
#pragma unroll
        for (int i = 0; i < 4; i++) {
          int id = tid + i * 512;
          *(uint4*)&nb[8192 + id * 8] = pb[i];       // B region linear
        }
      }
      __syncthreads();
      cur ^= 1;
    }

    // ---- cell fully in registers (gate-grouped layout) ----
    {
      f16* hhi_out = hhi + (size_t)bout * 1024 * 512;
      f16* hlo_out = hlo + (size_t)bout * 1024 * 512;
#pragma unroll
      for (int i = 0; i < 4; i++) {
        float gi = acc[0][i] + bias[0];
        float gf = acc[1][i] + bias[1];
        float gg = acc[2][i] + bias[2];
        float go = acc[3][i] + bias[3];
        float c = sigf(gf) * cc[i] + sigf(gi) * tanhf(gg);
        cc[i] = c;
        float h = sigf(go) * tanhf(c);
        size_t r = (size_t)(m0 + rg * 16 + (lane >> 4) * 4 + i) * 512 + jjcol;
        f16 h8 = (f16)h;
        hhi_out[r] = h8;
        hlo_out[r] = (f16)(h - (float)h8);
        if (s == 199) h_final[r] = h;
      }
    }

    // ---- per-mt 16-block barrier (release/acquire, monotonic count) ----
    __syncthreads();                    // drains vmcnt: h stores complete
    if (tid == 0) {
      __threadfence();                  // release (L2 writeback, device scope)
      atomicAdd(&bar[mt], 1u);
      unsigned target = 16u * (unsigned)(s + 1);
      while (atomicAdd(&bar[mt], 0u) < target) __builtin_amdgcn_s_sleep(8);
      __threadfence();                  // acquire (invalidate stale)
    }
    __syncthreads();
  }
}

// ============================= max(m) =======================================
__global__ void __launch_bounds__(1024)
maxm_kernel(const float* __restrict__ mv, float* __restrict__ out) {
  __shared__ float red[1024];
  int tid = threadIdx.x;
  float mx = -3.0e38f;
  for (int i = tid; i < 200 * 1024; i += 1024) mx = fmaxf(mx, mv[i]);
  red[tid] = mx;
  __syncthreads();
  for (int s = 512; s > 0; s >>= 1) {
    if (tid < s) red[tid] = fmaxf(red[tid], red[tid + s]);
    __syncthreads();
  }
  if (tid == 0) *out = red[0];
}

// ============ head layer 1: z = tanh(h @ {lw1,vw1}^T + b1) ==================
__global__ void __launch_bounds__(256, 2)
head1_valu(const float* __restrict__ h, const float* __restrict__ lw1,
           const float* __restrict__ lb1, const float* __restrict__ vw1,
           const float* __restrict__ vb1, float* __restrict__ z) {
  __shared__ float sAT[64 * 68];
  const int tid = threadIdx.x;
  const int rg = tid & 15;
  const int cgrp = tid >> 4;
  const int bid = blockIdx.x;
  const int mt = bid & 15, nt = bid >> 4;
  const int m0 = mt * 64;
  const int nb = nt * 64 + cgrp * 4;

  const float* wr[4];
  float bias[4];
  int hdv[4], wnv[4], valid[4];
#pragma unroll
  for (int c = 0; c < 4; c++) {
    int n = nb + c;
    valid[c] = (n < 1026);
    int hd = valid[c] ? (n >= 513) : 0;
    int wn = valid[c] ? (n - hd * 513) : 0;
    hdv[c] = hd; wnv[c] = wn;
    wr[c] = (hd ? vw1 : lw1) + (size_t)wn * 512;
    bias[c] = valid[c] ? (hd ? vb1[wn] : lb1[wn]) : 0.f;
  }

  float acc[4][4];
#pragma unroll
  for (int i = 0; i < 4; i++)
#pragma unroll
    for (int c = 0; c < 4; c++) acc[i][c] = 0.f;

  for (int ch = 0; ch < 8; ch++) {
    int k0 = ch * 64;
    for (int idx = tid; idx < 4096; idx += 256) {
      int row = idx >> 6, k = idx & 63;
      sAT[k * 68 + row] = h[(size_t)(m0 + row) * 512 + k0 + k];
    }
    __syncthreads();
#pragma unroll 4
    for (int k4 = 0; k4 < 16; k4++) {
      f32x4 wv[4];
#pragma unroll
      for (int c = 0; c < 4; c++)
        wv[c] = *(const f32x4*)(wr[c] + k0 + k4 * 4);
      f32x4 rv[4];
#pragma unroll
      for (int kk = 0; kk < 4; kk++)
        rv[kk] = *(const f32x4*)&sAT[(k4 * 4 + kk) * 68 + rg * 4];
#pragma unroll
      for (int kk = 0; kk < 4; kk++)
#pragma unroll
        for (int c = 0; c < 4; c++) {
          acc[0][c] += rv[kk][0] * wv[c][kk];
          acc[1][c] += rv[kk][1] * wv[c][kk];
          acc[2][c] += rv[kk][2] * wv[c][kk];
          acc[3][c] += rv[kk][3] * wv[c][kk];
        }
    }
    __syncthreads();
  }
#pragma unroll
  for (int c = 0; c < 4; c++) {
    if (!valid[c]) continue;
#pragma unroll
    for (int i = 0; i < 4; i++) {
      int m = m0 + rg * 4 + i;
      z[(size_t)hdv[c] * 1024 * 520 + (size_t)m * 520 + wnv[c]] =
          tanhf(acc[i][c] + bias[c]);
    }
  }
}

// ============ head layer 2: out = tanh(z @ {lw2,vw2}^T + b2) ================
__global__ void __launch_bounds__(256)
head2_valu(const float* __restrict__ z, const float* __restrict__ lw2,
           const float* __restrict__ lb2, const float* __restrict__ vw2,
           const float* __restrict__ vb2, float* __restrict__ out) {
  __shared__ float sZ[8 * 133];
  __shared__ float sW[32 * 133];
  const int tid = threadIdx.x;
  const int bid = blockIdx.x;
  const int gr0 = bid * 8;
  const int hd = gr0 >> 10;
  const int b0 = gr0 & 1023;
  const float* w2 = hd ? vw2 : lw2;
  const float* b2 = hd ? vb2 : lb2;
  const float* zh = z + (size_t)hd * 1024 * 520;
  const int rloc = tid >> 5, col = tid & 31;
  float acc = 0.f;

  for (int ch = 0; ch < 5; ch++) {
    int kc = ch * 128;
    for (int idx = tid; idx < 1024; idx += 256) {
      int row = idx >> 7, k = idx & 127;
      int kk = kc + k;
      sZ[row * 133 + k] = (kk < 513) ? zh[(size_t)(b0 + row) * 520 + kk] : 0.f;
    }
    for (int idx = tid; idx < 4096; idx += 256) {
      int row = idx >> 7, k = idx & 127;
      int kk = kc + k;
      sW[row * 133 + k] = (kk < 513) ? w2[(size_t)row * 513 + kk] : 0.f;
    }
    __syncthreads();
#pragma unroll 8
    for (int k = 0; k < 128; k++)
      acc += sZ[rloc * 133 + k] * sW[col * 133 + k];
    __syncthreads();
  }
  out[(size_t)hd * 32768 + (size_t)(b0 + rloc) * 32 + col] = tanhf(acc + b2[col]);
}

// ============================================================================
extern "C" void kernel_launch(void* const* d_in, const int* in_sizes, int n_in,
                              void* d_out, int out_size, void* d_ws, size_t ws_size,
                              hipStream_t stream) {
  (void)in_sizes; (void)n_in; (void)out_size; (void)ws_size;
  const float* x    = (const float*)d_in[0];
  const float* a    = (const float*)d_in[1];
  const float* mm   = (const float*)d_in[2];
  const float* w_ih = (const float*)d_in[3];
  const float* w_hh = (const float*)d_in[4];
  const float* b_ih = (const float*)d_in[5];
  const float* b_hh = (const float*)d_in[6];
  const float* lw1  = (const float*)d_in[7];
  const float* lb1  = (const float*)d_in[8];
  const float* lw2  = (const float*)d_in[9];
  const float* lb2  = (const float*)d_in[10];
  const float* vw1  = (const float*)d_in[11];
  const float* vb1  = (const float*)d_in[12];
  const float* vw2  = (const float*)d_in[13];
  const float* vb2  = (const float*)d_in[14];

  char* wsb = (char*)d_ws;
  float*    maxm  = (float*)wsb;                     // 256 B
  unsigned* bar   = (unsigned*)(wsb + 256);          // 16 u32 (zeroed by wprep)
  float*    z     = (float*)(wsb + 512);             // 2x1024x520 f32
  float*    h_fin = (float*)(wsb + 4260352);         // 1024x512 f32
  uint4*    wsw   = (uint4*)(wsb + 6357504);         // 294912 uint4 = 4.5 MB
  f16*      hhi   = (f16*)(wsb + 11076096);          // [2][1024][512] f16
  f16*      hlo   = (f16*)(wsb + 13173248);          // [2][1024][512] f16

  maxm_kernel<<<1, 1024, 0, stream>>>(mm, maxm);
  wprep_kernel<<<1152, 256, 0, stream>>>(w_ih, w_hh, wsw, bar);

  {
    const float* xa = x; const float* aa = a;
    const uint4* wswa = wsw;
    const float* biha = b_ih; const float* bhha = b_hh;
    f16* hhia = hhi; f16* hloa = hlo;
    float* hfa = h_fin; const float* mxa = maxm;
    unsigned* bara = bar;
    void* kargs[] = {&xa, &aa, &wswa, &biha, &bhha,
                     &hhia, &hloa, &hfa, &mxa, &bara};
    hipLaunchCooperativeKernel((void*)lstm_persist, dim3(256), dim3(512),
                               kargs, 0, stream);
  }

  head1_valu<<<272, 256, 0, stream>>>(h_fin, lw1, lb1, vw1, vb1, z);
  head2_valu<<<256, 256, 0, stream>>>(z, lw2, lb2, vw2, vb2, (float*)d_out);
}

// Round 6
// 7427.177 us; speedup vs baseline: 1.3474x; 1.1510x over previous
//
#include <hip/hip_runtime.h>
#include <cstdint>

// ============================================================================
// EncoderLSTMReal: reverse LSTM (T=200,B=1024,H=512,IN=64) + 2 tanh-MLP heads.
// CONTRACT (R0-R8): inputs fp32 dict order; OUTPUT FLOAT32 (mu 0..32768, lv
// next); heads read fp32 h_final.
// Round-15 (R6): per-step launches + R5's gate-grouped MFMA body.
//   R5 post-mortem: persistent kernel's per-step device-scope fence forces
//   full L2 wb+inv on every XCD every step (FETCH identical to R4's 1.84 GB;
//   MfmaUtil 6.9%, 85% idle). Kernel boundary IS the cheap device barrier.
//   Body kept from R5 (verified absmax 0.00195): wave = 16 rows x 16 jj x
//   all 4 gates -> LSTM cell fully in registers; B staged from wprep-
//   preswizzled images (coalesced uint4 -> linear LDS); split-fp16 3-MFMA.
//   New: c persists across launches in thread-linear c_perm (coalesced
//   f32x4, aliases z region); biases pre-summed (bsum) by wprep.
//   grid 256 = 16 mt x 16 jt; block 512 = 8 waves; LDS 96 KB dbuf ->
//   1 block/CU, 2 waves/SIMD.
// ws: maxm@0; c_perm/z@512 (c_perm during LSTM, z after); h_final@4260352;
//     wsw@6357504 (4.5MB); bsum@11076096; hhi@11084288; hlo@13181440.
// ============================================================================

typedef _Float16 f16;
typedef __attribute__((ext_vector_type(8))) _Float16 f16x8;
typedef __attribute__((ext_vector_type(4))) float f32x4;

#define DEV __device__ __forceinline__

DEV float sigf(float x) { return 1.0f / (1.0f + expf(-x)); }

// ============ weight pre-swizzle + bias pre-sum =============================
// wsw uint4 idx = ((jt*9 + ch)*32 + Lb)*64 + lane, Lb = ((g*2+jg)*2+ks)*2+p.
// value: 8 halves of plane p of w[n][kb..kb+7], n = g*512+jt*32+jg*16+(lane&15),
// kb = ch*64 + ks*32 + (lane>>4)*8.  (k<64 -> w_ih, else w_hh.)
__global__ void __launch_bounds__(256)
wprep_kernel(const float* __restrict__ w_ih, const float* __restrict__ w_hh,
             uint4* __restrict__ wsw, const float* __restrict__ b_ih,
             const float* __restrict__ b_hh, float* __restrict__ bsum) {
  int idx = blockIdx.x * 256 + threadIdx.x;       // 1152*256 = 294912 exact
  if (idx < 2048) bsum[idx] = b_ih[idx] + b_hh[idx];
  if (idx >= 16 * 9 * 32 * 64) return;
  int jt = idx / 18432, rem = idx - jt * 18432;
  int ch = rem >> 11, r2 = rem & 2047;
  int Lb = r2 >> 6, lane = r2 & 63;
  int p = Lb & 1, ks = (Lb >> 1) & 1, jg = (Lb >> 2) & 1, g = Lb >> 3;
  int n = g * 512 + jt * 32 + jg * 16 + (lane & 15);
  int kb = ch * 64 + ks * 32 + (lane >> 4) * 8;
  f16x8 o;
#pragma unroll
  for (int e = 0; e < 8; e++) {
    int k = kb + e;
    float v = (k < 64) ? w_ih[n * 64 + k] : w_hh[(size_t)n * 512 + (k - 64)];
    f16 hi = (f16)v;
    o[e] = p ? (f16)(v - (float)hi) : hi;
  }
  wsw[idx] = *(uint4*)&o;
}

// ============================ per-step LSTM =================================
// grid 256 = 16 mt x 16 jt; block 512 = 8 waves = 4 rg x 2 jg.
// wave (rg,jg): rows m0+rg*16..+15, cols = 4 gates x (jt*32 + jg*16 ..+15).
// LDS buf (48 KB): A lines 0..15 (id=(rg*2+ks)*2+p), B lines 16..47 (16+Lb);
// line = 64 lanes x 8 halves; slot addressing LINEAR in stage id.
__global__ void __launch_bounds__(512)
lstm_step(const float* __restrict__ x, const float* __restrict__ a,
          const uint4* __restrict__ wsw, const float* __restrict__ bsum,
          const f16* __restrict__ hhi_in, const f16* __restrict__ hlo_in,
          f16* __restrict__ hhi_out, f16* __restrict__ hlo_out,
          float* __restrict__ c_perm, float* __restrict__ h_final,
          const float* __restrict__ maxm_p, int s) {
  __shared__ f16 sAB[2][24576];     // [buf][ A: 8192 halves | B: 16384 ]

  const int tid = threadIdx.x;
  const int lane = tid & 63;
  const int w = tid >> 6;
  const int rg = w >> 1, jg = w & 1;
  const int bid = blockIdx.x;
  const int mt = bid >> 4, jt = bid & 15;
  const int m0 = mt * 64;
  const int jjcol = jt * 32 + jg * 16 + (lane & 15);

  float bias[4];
#pragma unroll
  for (int g = 0; g < 4; g++) bias[g] = bsum[g * 512 + jjcol];
  f32x4 cc = {0.f, 0.f, 0.f, 0.f};
  if (s > 0) cc = *(const f32x4*)&c_perm[(size_t)(bid * 512 + tid) * 4];

  const int nch = (s == 0) ? 1 : 9;

  // ---- prologue: stage chunk 0 (x|a|t split hi/lo) + B chunk 0 ----
  {
#pragma unroll
    for (int i = 0; i < 4; i++) {
      int id = tid + i * 512;
      uint4 v = wsw[(size_t)(jt * 9 + 0) * 2048 + id];
      *(uint4*)&sAB[0][8192 + id * 8] = v;
    }
    const float ts = (float)s / (*maxm_p);
    size_t srow = (size_t)(199 - s) * 1024 + m0;
    int row = tid >> 3, k8 = (tid & 7) * 8;
    float v[8];
#pragma unroll
    for (int e = 0; e < 8; e++) {
      int k = k8 + e;
      if (k < 48)      v[e] = x[(srow + row) * 48 + k];
      else if (k < 63) v[e] = a[(srow + row) * 15 + (k - 48)];
      else             v[e] = ts;
    }
    f16x8 hi, lo;
#pragma unroll
    for (int e = 0; e < 8; e++) {
      f16 h8 = (f16)v[e];
      hi[e] = h8; lo[e] = (f16)(v[e] - (float)h8);
    }
    int rg2 = row >> 4, ks2 = k8 >> 5;
    int ln = (((k8 & 31) >> 3) << 4) | (row & 15);
    int Lhi = (rg2 * 2 + ks2) * 2;
    *(f16x8*)&sAB[0][(Lhi * 64 + ln) * 8] = hi;
    *(f16x8*)&sAB[0][((Lhi + 1) * 64 + ln) * 8] = lo;
  }
  __syncthreads();

  f32x4 acc[4];
#pragma unroll
  for (int g = 0; g < 4; g++) acc[g] = (f32x4){0.f, 0.f, 0.f, 0.f};

  int cur = 0;
  for (int ch = 0; ch < nch; ch++) {
    const bool pref = (ch + 1 < nch);
    uint4 pa[2], pb[4];
    if (pref) {
#pragma unroll
      for (int i = 0; i < 2; i++) {            // A: h chunk ch (k = ch*64+..)
        int id = tid + i * 512;
        int La = id >> 6, ln = id & 63;
        int rg2 = La >> 2, ks2 = (La >> 1) & 1, p2 = La & 1;
        const f16* pl = p2 ? hlo_in : hhi_in;
        size_t ad = (size_t)(m0 + rg2 * 16 + (ln & 15)) * 512 +
                    ch * 64 + ks2 * 32 + (ln >> 4) * 8;
        pa[i] = *(const uint4*)&pl[ad];
      }
#pragma unroll
      for (int i = 0; i < 4; i++) {            // B: chunk ch+1 image
        int id = tid + i * 512;
        pb[i] = wsw[(size_t)(jt * 9 + ch + 1) * 2048 + id];
      }
    }

    const f16* buf = sAB[cur];
#pragma unroll
    for (int ks = 0; ks < 2; ks++) {
      f16x8 Ah = *(const f16x8*)&buf[(((rg * 2 + ks) * 2 + 0) * 64 + lane) * 8];
      f16x8 Al = *(const f16x8*)&buf[(((rg * 2 + ks) * 2 + 1) * 64 + lane) * 8];
      f16x8 Bh[4], Bl[4];
#pragma unroll
      for (int g = 0; g < 4; g++) {
        int base = 8192 + ((((g * 2 + jg) * 2 + ks) * 2) * 64 + lane) * 8;
        Bh[g] = *(const f16x8*)&buf[base];
        Bl[g] = *(const f16x8*)&buf[base + 512];   // +1 line = 64*8 halves
      }
      __builtin_amdgcn_s_setprio(1);
#pragma unroll
      for (int g = 0; g < 4; g++)
        acc[g] = __builtin_amdgcn_mfma_f32_16x16x32_f16(Ah, Bh[g], acc[g], 0, 0, 0);
#pragma unroll
      for (int g = 0; g < 4; g++)
        acc[g] = __builtin_amdgcn_mfma_f32_16x16x32_f16(Al, Bh[g], acc[g], 0, 0, 0);
#pragma unroll
      for (int g = 0; g < 4; g++)
        acc[g] = __builtin_amdgcn_mfma_f32_16x16x32_f16(Ah, Bl[g], acc[g], 0, 0, 0);
      __builtin_amdgcn_s_setprio(0);
    }

    if (pref) {
      f16* nb = sAB[cur ^ 1];
#pragma unroll
      for (int i = 0; i < 2; i++) {
        int id = tid + i * 512;
        *(uint4*)&nb[id * 8] = pa[i];              // A region linear
      }
#pragma unroll
      for (int i = 0; i < 4; i++) {
        int id = tid + i * 512;
        *(uint4*)&nb[8192 + id * 8] = pb[i];       // B region linear
      }
    }
    __syncthreads();
    cur ^= 1;
  }

  // ---- cell fully in registers (gate-grouped layout) ----
  {
#pragma unroll
    for (int i = 0; i < 4; i++) {
      float gi = acc[0][i] + bias[0];
      float gf = acc[1][i] + bias[1];
      float gg = acc[2][i] + bias[2];
      float go = acc[3][i] + bias[3];
      float c = sigf(gf) * cc[i] + sigf(gi) * tanhf(gg);
      cc[i] = c;
      float h = sigf(go) * tanhf(c);
      size_t r = (size_t)(m0 + rg * 16 + (lane >> 4) * 4 + i) * 512 + jjcol;
      f16 h8 = (f16)h;
      hhi_out[r] = h8;
      hlo_out[r] = (f16)(h - (float)h8);
      if (s == 199) h_final[r] = h;
    }
    *(f32x4*)&c_perm[(size_t)(bid * 512 + tid) * 4] = cc;
  }
}

// ============================= max(m) =======================================
__global__ void __launch_bounds__(1024)
maxm_kernel(const float* __restrict__ mv, float* __restrict__ out) {
  __shared__ float red[1024];
  int tid = threadIdx.x;
  float mx = -3.0e38f;
  for (int i = tid; i < 200 * 1024; i += 1024) mx = fmaxf(mx, mv[i]);
  red[tid] = mx;
  __syncthreads();
  for (int s = 512; s > 0; s >>= 1) {
    if (tid < s) red[tid] = fmaxf(red[tid], red[tid + s]);
    __syncthreads();
  }
  if (tid == 0) *out = red[0];
}

// ============ head layer 1: z = tanh(h @ {lw1,vw1}^T + b1) ==================
__global__ void __launch_bounds__(256, 2)
head1_valu(const float* __restrict__ h, const float* __restrict__ lw1,
           const float* __restrict__ lb1, const float* __restrict__ vw1,
           const float* __restrict__ vb1, float* __restrict__ z) {
  __shared__ float sAT[64 * 68];
  const int tid = threadIdx.x;
  const int rg = tid & 15;
  const int cgrp = tid >> 4;
  const int bid = blockIdx.x;
  const int mt = bid & 15, nt = bid >> 4;
  const int m0 = mt * 64;
  const int nb = nt * 64 + cgrp * 4;

  const float* wr[4];
  float bias[4];
  int hdv[4], wnv[4], valid[4];
#pragma unroll
  for (int c = 0; c < 4; c++) {
    int n = nb + c;
    valid[c] = (n < 1026);
    int hd = valid[c] ? (n >= 513) : 0;
    int wn = valid[c] ? (n - hd * 513) : 0;
    hdv[c] = hd; wnv[c] = wn;
    wr[c] = (hd ? vw1 : lw1) + (size_t)wn * 512;
    bias[c] = valid[c] ? (hd ? vb1[wn] : lb1[wn]) : 0.f;
  }

  float acc[4][4];
#pragma unroll
  for (int i = 0; i < 4; i++)
#pragma unroll
    for (int c = 0; c < 4; c++) acc[i][c] = 0.f;

  for (int ch = 0; ch < 8; ch++) {
    int k0 = ch * 64;
    for (int idx = tid; idx < 4096; idx += 256) {
      int row = idx >> 6, k = idx & 63;
      sAT[k * 68 + row] = h[(size_t)(m0 + row) * 512 + k0 + k];
    }
    __syncthreads();
#pragma unroll 4
    for (int k4 = 0; k4 < 16; k4++) {
      f32x4 wv[4];
#pragma unroll
      for (int c = 0; c < 4; c++)
        wv[c] = *(const f32x4*)(wr[c] + k0 + k4 * 4);
      f32x4 rv[4];
#pragma unroll
      for (int kk = 0; kk < 4; kk++)
        rv[kk] = *(const f32x4*)&sAT[(k4 * 4 + kk) * 68 + rg * 4];
#pragma unroll
      for (int kk = 0; kk < 4; kk++)
#pragma unroll
        for (int c = 0; c < 4; c++) {
          acc[0][c] += rv[kk][0] * wv[c][kk];
          acc[1][c] += rv[kk][1] * wv[c][kk];
          acc[2][c] += rv[kk][2] * wv[c][kk];
          acc[3][c] += rv[kk][3] * wv[c][kk];
        }
    }
    __syncthreads();
  }
#pragma unroll
  for (int c = 0; c < 4; c++) {
    if (!valid[c]) continue;
#pragma unroll
    for (int i = 0; i < 4; i++) {
      int m = m0 + rg * 4 + i;
      z[(size_t)hdv[c] * 1024 * 520 + (size_t)m * 520 + wnv[c]] =
          tanhf(acc[i][c] + bias[c]);
    }
  }
}

// ============ head layer 2: out = tanh(z @ {lw2,vw2}^T + b2) ================
__global__ void __launch_bounds__(256)
head2_valu(const float* __restrict__ z, const float* __restrict__ lw2,
           const float* __restrict__ lb2, const float* __restrict__ vw2,
           const float* __restrict__ vb2, float* __restrict__ out) {
  __shared__ float sZ[8 * 133];
  __shared__ float sW[32 * 133];
  const int tid = threadIdx.x;
  const int bid = blockIdx.x;
  const int gr0 = bid * 8;
  const int hd = gr0 >> 10;
  const int b0 = gr0 & 1023;
  const float* w2 = hd ? vw2 : lw2;
  const float* b2 = hd ? vb2 : lb2;
  const float* zh = z + (size_t)hd * 1024 * 520;
  const int rloc = tid >> 5, col = tid & 31;
  float acc = 0.f;

  for (int ch = 0; ch < 5; ch++) {
    int kc = ch * 128;
    for (int idx = tid; idx < 1024; idx += 256) {
      int row = idx >> 7, k = idx & 127;
      int kk = kc + k;
      sZ[row * 133 + k] = (kk < 513) ? zh[(size_t)(b0 + row) * 520 + kk] : 0.f;
    }
    for (int idx = tid; idx < 4096; idx += 256) {
      int row = idx >> 7, k = idx & 127;
      int kk = kc + k;
      sW[row * 133 + k] = (kk < 513) ? w2[(size_t)row * 513 + kk] : 0.f;
    }
    __syncthreads();
#pragma unroll 8
    for (int k = 0; k < 128; k++)
      acc += sZ[rloc * 133 + k] * sW[col * 133 + k];
    __syncthreads();
  }
  out[(size_t)hd * 32768 + (size_t)(b0 + rloc) * 32 + col] = tanhf(acc + b2[col]);
}

// ============================================================================
extern "C" void kernel_launch(void* const* d_in, const int* in_sizes, int n_in,
                              void* d_out, int out_size, void* d_ws, size_t ws_size,
                              hipStream_t stream) {
  (void)in_sizes; (void)n_in; (void)out_size; (void)ws_size;
  const float* x    = (const float*)d_in[0];
  const float* a    = (const float*)d_in[1];
  const float* mm   = (const float*)d_in[2];
  const float* w_ih = (const float*)d_in[3];
  const float* w_hh = (const float*)d_in[4];
  const float* b_ih = (const float*)d_in[5];
  const float* b_hh = (const float*)d_in[6];
  const float* lw1  = (const float*)d_in[7];
  const float* lb1  = (const float*)d_in[8];
  const float* lw2  = (const float*)d_in[9];
  const float* lb2  = (const float*)d_in[10];
  const float* vw1  = (const float*)d_in[11];
  const float* vb1  = (const float*)d_in[12];
  const float* vw2  = (const float*)d_in[13];
  const float* vb2  = (const float*)d_in[14];

  char* wsb = (char*)d_ws;
  float* maxm   = (float*)wsb;                       // 256 B
  float* c_perm = (float*)(wsb + 512);               // 2 MB (aliases z: LSTM-only)
  float* z      = (float*)(wsb + 512);               // 2x1024x520 f32 (heads)
  float* h_fin  = (float*)(wsb + 4260352);           // 1024x512 f32
  uint4* wsw    = (uint4*)(wsb + 6357504);           // 294912 uint4 = 4.5 MB
  float* bsum   = (float*)(wsb + 11076096);          // 2048 f32
  f16*   hhi    = (f16*)(wsb + 11084288);            // [2][1024][512] f16
  f16*   hlo    = (f16*)(wsb + 13181440);            // [2][1024][512] f16

  maxm_kernel<<<1, 1024, 0, stream>>>(mm, maxm);
  wprep_kernel<<<1152, 256, 0, stream>>>(w_ih, w_hh, wsw, b_ih, b_hh, bsum);

  for (int s = 0; s < 200; s++) {
    const int bin = s & 1, bout = bin ^ 1;
    lstm_step<<<256, 512, 0, stream>>>(
        x, a, wsw, bsum,
        hhi + (size_t)bin * 1024 * 512, hlo + (size_t)bin * 1024 * 512,
        hhi + (size_t)bout * 1024 * 512, hlo + (size_t)bout * 1024 * 512,
        c_perm, h_fin, maxm, s);
  }

  head1_valu<<<272, 256, 0, stream>>>(h_fin, lw1, lb1, vw1, vb1, z);
  head2_valu<<<256, 256, 0, stream>>>(z, lw2, lb2, vw2, vb2, (float*)d_out);
}